// Round 7
// baseline (104.934 us; speedup 1.0000x reference)
//
#include <hip/hip_runtime.h>
#include <hip/hip_bf16.h>
#include <stdint.h>

#define KD 512
#define OD 8
#define SZ (KD*KD*OD)       // 2097152 elements per tensor (A,B,C)
#define PLANE (KD*KD)       // 262144

typedef short v8s __attribute__((ext_vector_type(8)));
typedef float v4f __attribute__((ext_vector_type(4)));

static __device__ __forceinline__ unsigned short f2bf(float f) {
    union { float f; unsigned int u; } v; v.f = f;
    unsigned int u = v.u;
    unsigned int r = u + 0x7FFF + ((u >> 16) & 1);   // RNE
    return (unsigned short)(r >> 16);
}

// ---------------------------------------------------------------------------
// FRAGMENT LAYOUT v2 (k-major), one MFMA operand fragment = one coalesced
// 1 KB wave load, and ADJACENT row-tiles are only 512 elems (1 KB) apart so
// the mt/nt-neighbor load folds into the 13-bit immediate offset (4 base
// pointers total instead of 8 -> fits the 128-VGPR budget for 4 blocks/CU):
//   plane p, row r, col k ->
//   elem_off = p*PLANE + (k>>5)*16384 + (r>>4)*512
//            + ((r&15) + ((k>>3)&3)*16)*8 + (k&7)
// i.e. F[p][kc16][rt32][lane64][8], lane = (r&15) + ((k>>3)&3)*16 — exactly
// the mfma_f32_16x16x32_bf16 operand lane map (verified by R6 passing).
// ---------------------------------------------------------------------------

__global__ __launch_bounds__(256) void pack_kernel(const float* __restrict__ yp,
                                                   unsigned short* __restrict__ Wbf,
                                                   unsigned short* __restrict__ Xbf,
                                                   float* __restrict__ probs_acc) {
    __shared__ unsigned short lds[8 * 32 * 32];   // [y][di][dk] 64B rows, swizzled
    const float* Pa = yp;
    const float* Pb = yp + KD;
    const float* Pc = yp + 2 * KD;
    const float* A  = yp + 3 * KD;
    const float* B  = A + SZ;
    const int b = blockIdx.x;
    const int t = threadIdx.x;

    if (b == 0) { probs_acc[t] = 0.0f; probs_acc[t + 256] = 0.0f; }

    if (b < 256) {
        // ---- A-pack: j = 2b, 2b+1; each thread handles k0 = 2t, 2t+1 ----
        #pragma unroll
        for (int jj = 0; jj < 2; ++jj) {
            const int j = b * 2 + jj;
            const float pb = Pb[j];
            const int k0 = 2 * t;
            const float4* src = (const float4*)(A + ((size_t)j * KD + k0) * 8);
            float av[16];
            ((float4*)av)[0] = src[0];
            ((float4*)av)[1] = src[1];
            ((float4*)av)[2] = src[2];
            ((float4*)av)[3] = src[3];
            const float s0 = pb * Pc[k0];
            const float s1 = pb * Pc[k0 + 1];
            // k-major fragment offset for (j, k0); k0 even so the ushort2
            // (k0,k0+1) stays inside one 8-elem lane slot.
            const size_t fo = (size_t)(k0 >> 5) * 16384 + (size_t)(j >> 4) * 512
                            + (size_t)((k0 >> 3) & 3) * 128 + (j & 15) * 8 + (k0 & 7);
            #pragma unroll
            for (int x = 0; x < 8; ++x) {
                ushort2 w;
                w.x = f2bf(av[x] * s0);
                w.y = f2bf(av[8 + x] * s1);
                *(ushort2*)(Wbf + (size_t)x * PLANE + fo) = w;
            }
        }
    } else {
        // ---- B-pack: transpose [k][i] -> [i][k] through swizzled LDS ----
        const int tb = b - 256;
        const int k0 = (tb / 16) * 32;
        const int i0 = (tb % 16) * 32;
        char* ldsb = (char*)lds;
        #pragma unroll
        for (int p = 0; p < 4; ++p) {
            const int idx = t + p * 256;
            const int dk = idx >> 5;
            const int di = idx & 31;
            const float pa = Pa[i0 + di];
            const float4* src = (const float4*)(B + ((size_t)(k0 + dk) * KD + (i0 + di)) * 8);
            float bv[8];
            ((float4*)bv)[0] = src[0];
            ((float4*)bv)[1] = src[1];
            const int swz = (di & 7) << 4;
            #pragma unroll
            for (int y = 0; y < 8; ++y)
                *(unsigned short*)(ldsb + (y * 32 + di) * 64 + ((dk * 2) ^ swz)) =
                    f2bf(bv[y] * pa);
        }
        __syncthreads();
        #pragma unroll
        for (int p = 0; p < 4; ++p) {
            const int c = t + p * 256;
            const int y = c >> 7;
            const int rem = c & 127;
            const int di = rem >> 2;
            const int dk8 = (rem & 3) * 8;   // 8-aligned k offset within 32-chunk
            uint4 v = *(const uint4*)(ldsb + (y * 32 + di) * 64 + ((dk8 * 2) ^ ((di & 7) << 4)));
            const size_t fo = (size_t)(k0 >> 5) * 16384 + (size_t)((i0 + di) >> 4) * 512
                            + (size_t)(dk8 >> 3) * 128 + (di & 15) * 8;
            *(uint4*)(Xbf + (size_t)y * PLANE + fo) = v;
        }
    }
}

// ---------------------------------------------------------------------------
// Fused GEMM + C-contraction — FRAGMENT-DIRECT + FULL RESIDENCY.
// R2/R5/R6 all plateaued at ~45 us with 3 different schedules -> shared
// bottleneck = the straggler round: grid 1024 at 3 blocks/CU leaves a tail
// round of 1 block/CU (~2x the ideal wall time for a latency-bound loop).
// Fix: __launch_bounds__(256, 4) -> 4 blocks/CU, ALL 1024 blocks resident
// in ONE round, no tail.  Register budget for 4 waves/SIMD is 128/wave:
// acc 64 + transient frags 32 + 4 base pointers (k-major layout v2 puts
// the mt/nt-neighbor 1 KB away = immediate offset) + ~10 scalars -> fits.
// No LDS, no barriers, no setprio (T5 prereq absent; risks fencing loads).
// XCD swizzle kept: per-XCD working set ~4 MB = one L2.
// ---------------------------------------------------------------------------
__global__ __launch_bounds__(256, 4) void gemm_kernel(const float* __restrict__ yp,
                                                      const unsigned short* __restrict__ Wbf,
                                                      const unsigned short* __restrict__ Xbf,
                                                      float* __restrict__ probs_acc) {
    __shared__ float red[4][32];

    const int bid = blockIdx.x;
    const int xcd = bid & 7;
    const int local = bid >> 3;          // 0..127
    const int tl = local >> 4;           // 0..7  tile-local
    const int group = local & 15;        // 0..15 xy-group
    const int i_t = ((xcd >> 1) << 1) | (tl >> 2);   // 0..7
    const int j_t = ((xcd & 1) << 2) | (tl & 3);     // 0..7
    const int i0 = i_t * 64, j0 = j_t * 64;
    const int x0 = (group >> 2) * 2, y0 = (group & 3) * 2;

    const int t = threadIdx.x;
    const int w = t >> 6;            // wave 0..3
    const int l = t & 63;
    const int wm = w >> 1, wn = w & 1;
    const int lm = l & 15, quad = l >> 4;

    // 4 base pointers; mt/nt tile = +512 elems (1 KB imm), kt = +16384 elems.
    const unsigned short* aP[2];   // [dy]
    const unsigned short* bP[2];   // [dx]
    #pragma unroll
    for (int dy = 0; dy < 2; ++dy)
        aP[dy] = Xbf + (size_t)(y0 + dy) * PLANE
               + (size_t)((i0 + wm * 32) >> 4) * 512 + l * 8;
    #pragma unroll
    for (int dx = 0; dx < 2; ++dx)
        bP[dx] = Wbf + (size_t)(x0 + dx) * PLANE
               + (size_t)((j0 + wn * 32) >> 4) * 512 + l * 8;

    v4f acc[2][2][2][2];   // [dy][dx][mt][nt]
    #pragma unroll
    for (int a = 0; a < 2; ++a)
      #pragma unroll
      for (int bb = 0; bb < 2; ++bb)
        #pragma unroll
        for (int c = 0; c < 2; ++c)
          #pragma unroll
          for (int d = 0; d < 2; ++d)
            acc[a][bb][c][d] = (v4f){0.f, 0.f, 0.f, 0.f};

    // 16 K-steps of 32.  8 coalesced 1 KB loads + 16 MFMA each.  No barriers,
    // no fences: the scheduler hoists step kt+1's loads under kt's MFMAs.
    #pragma unroll 4
    for (int kt = 0; kt < 16; ++kt) {
        const int kof = kt * 16384;
        v8s aF[2][2], bF[2][2];
        #pragma unroll
        for (int dy = 0; dy < 2; ++dy)
            #pragma unroll
            for (int mt = 0; mt < 2; ++mt)
                aF[dy][mt] = *(const v8s*)(aP[dy] + kof + mt * 512);
        #pragma unroll
        for (int dx = 0; dx < 2; ++dx)
            #pragma unroll
            for (int nt = 0; nt < 2; ++nt)
                bF[dx][nt] = *(const v8s*)(bP[dx] + kof + nt * 512);
        #pragma unroll
        for (int dy = 0; dy < 2; ++dy)
            #pragma unroll
            for (int dx = 0; dx < 2; ++dx)
                #pragma unroll
                for (int mt = 0; mt < 2; ++mt)
                    #pragma unroll
                    for (int nt = 0; nt < 2; ++nt)
                        acc[dy][dx][mt][nt] = __builtin_amdgcn_mfma_f32_16x16x32_bf16(
                            aF[dy][mt], bF[dx][nt], acc[dy][dx][mt][nt], 0, 0, 0);
    }

    // ---- epilogue: contract 4 T tiles with shared C[i,j,0..7] (fp32, L2) ----
    const float* Cp = yp + 3 * KD + 2 * (size_t)SZ;
    float zacc[2][2][8];
    #pragma unroll
    for (int dy = 0; dy < 2; ++dy)
      #pragma unroll
      for (int dx = 0; dx < 2; ++dx)
        #pragma unroll
        for (int z = 0; z < 8; ++z) zacc[dy][dx][z] = 0.f;

    #pragma unroll
    for (int mt = 0; mt < 2; ++mt) {
        #pragma unroll
        for (int nt = 0; nt < 2; ++nt) {
            #pragma unroll
            for (int r = 0; r < 4; ++r) {
                const int gi = i0 + wm * 32 + mt * 16 + quad * 4 + r;  // D row = i
                const int gj = j0 + wn * 32 + nt * 16 + lm;            // D col = j
                const float4* cp = (const float4*)(Cp + ((size_t)gi * KD + gj) * 8);
                const float4 c0 = cp[0], c1 = cp[1];
                #pragma unroll
                for (int dy = 0; dy < 2; ++dy) {
                    #pragma unroll
                    for (int dx = 0; dx < 2; ++dx) {
                        const float tv = acc[dy][dx][mt][nt][r];
                        zacc[dy][dx][0] += tv * c0.x; zacc[dy][dx][1] += tv * c0.y;
                        zacc[dy][dx][2] += tv * c0.z; zacc[dy][dx][3] += tv * c0.w;
                        zacc[dy][dx][4] += tv * c1.x; zacc[dy][dx][5] += tv * c1.y;
                        zacc[dy][dx][6] += tv * c1.z; zacc[dy][dx][7] += tv * c1.w;
                    }
                }
            }
        }
    }
    #pragma unroll
    for (int dy = 0; dy < 2; ++dy)
      #pragma unroll
      for (int dx = 0; dx < 2; ++dx)
        #pragma unroll
        for (int z = 0; z < 8; ++z) {
            float v = zacc[dy][dx][z];
            for (int off = 32; off > 0; off >>= 1)
                v += __shfl_xor(v, off, 64);
            zacc[dy][dx][z] = v;
        }
    if (l == 0) {
        #pragma unroll
        for (int dy = 0; dy < 2; ++dy)
          #pragma unroll
          for (int dx = 0; dx < 2; ++dx)
            #pragma unroll
            for (int z = 0; z < 8; ++z)
                red[w][(dy * 2 + dx) * 8 + z] = zacc[dy][dx][z];
    }
    __syncthreads();
    if (t < 32) {
        const float s = red[0][t] + red[1][t] + red[2][t] + red[3][t];
        const int p = t >> 3;              // dy*2+dx
        const int dy = p >> 1, dx = p & 1, z = t & 7;
        atomicAdd(&probs_acc[((x0 + dx) * 8 + (y0 + dy)) * 8 + z], s);
    }
}

// ---------------------------------------------------------------------------
// Finalize: KL divergence + emit probs. out[0]=d, out[1..512]=probs.
// ---------------------------------------------------------------------------
__global__ __launch_bounds__(512) void finalize_kernel(const float* __restrict__ probs_acc,
                                                       const float* __restrict__ y_true,
                                                       float* __restrict__ out) {
    __shared__ float red[8];
    const int t = threadIdx.x;
    const float p = probs_acc[t];
    out[1 + t] = p;
    const float ytv = y_true[t];
    const float pc = fminf(fmaxf(p, 1e-10f), 1.0f);
    float term = ytv * (logf(ytv + 1e-10f) - logf(pc));
    for (int off = 32; off > 0; off >>= 1)
        term += __shfl_xor(term, off, 64);
    if ((t & 63) == 0) red[t >> 6] = term;
    __syncthreads();
    if (t == 0) {
        float s = 0.f;
        #pragma unroll
        for (int i = 0; i < 8; ++i) s += red[i];
        out[0] = s;
    }
}

extern "C" void kernel_launch(void* const* d_in, const int* in_sizes, int n_in,
                              void* d_out, int out_size, void* d_ws, size_t ws_size,
                              hipStream_t stream) {
    const float* yp = (const float*)d_in[0];
    const float* yt = (const float*)d_in[1];
    float* out = (float*)d_out;

    unsigned short* Wbf = (unsigned short*)d_ws;              // 8 planes of A-weighted: 4 MB
    unsigned short* Xbf = Wbf + (size_t)8 * PLANE;            // 8 planes of B-weighted: 4 MB
    float* probs_acc = (float*)(Xbf + (size_t)8 * PLANE);     // 512 floats

    pack_kernel<<<512, 256, 0, stream>>>(yp, Wbf, Xbf, probs_acc);
    gemm_kernel<<<1024, 256, 0, stream>>>(yp, Wbf, Xbf, probs_acc);
    finalize_kernel<<<1, 512, 0, stream>>>(probs_acc, yt, out);
}

// Round 8
// 102.351 us; speedup vs baseline: 1.0252x; 1.0252x over previous
//
#include <hip/hip_runtime.h>
#include <hip/hip_bf16.h>
#include <stdint.h>

#define KD 512
#define OD 8
#define SZ (KD*KD*OD)       // 2097152 elements per tensor (A,B,C)
#define PLANE (KD*KD)       // 262144

typedef short v8s __attribute__((ext_vector_type(8)));
typedef float v4f __attribute__((ext_vector_type(4)));

#define GLOBAL_AS __attribute__((address_space(1)))
#define LDS_AS __attribute__((address_space(3)))

static __device__ __forceinline__ unsigned short f2bf(float f) {
    union { float f; unsigned int u; } v; v.f = f;
    unsigned int u = v.u;
    unsigned int r = u + 0x7FFF + ((u >> 16) & 1);   // RNE
    return (unsigned short)(r >> 16);
}

static __device__ __forceinline__ void async16(const unsigned short* g, unsigned short* l) {
    __builtin_amdgcn_global_load_lds((const GLOBAL_AS void*)g, (LDS_AS void*)l, 16, 0, 0);
}

static __device__ __forceinline__ void bar() {
    __builtin_amdgcn_sched_barrier(0);
    __builtin_amdgcn_s_barrier();
    __builtin_amdgcn_sched_barrier(0);
}

// ---------------------------------------------------------------------------
// FRAGMENT LAYOUT v2 (k-major): one MFMA operand fragment (rt = 16 rows,
// kc = 32 k) = 512 contiguous elems (1 KB):
//   elem_off = p*PLANE + (k>>5)*16384 + (r>>4)*512
//            + ((k>>3)&3)*128 + (r&15)*8 + (k&7)
// lane l owns elems [l*8, l*8+8) = mfma_f32_16x16x32_bf16 operand map
// (verified by R6/R7 passing).  Staging a fragment line into LDS is a
// linear 1 KB copy -> global_load_lds legal, ds_read_b128 at lane*16B is
// conflict-free by construction (no swizzle machinery needed).
// ---------------------------------------------------------------------------

__global__ __launch_bounds__(256) void pack_kernel(const float* __restrict__ yp,
                                                   unsigned short* __restrict__ Wbf,
                                                   unsigned short* __restrict__ Xbf,
                                                   float* __restrict__ probs_acc) {
    __shared__ unsigned short lds[8 * 32 * 32];   // [y][di][dk] 64B rows, swizzled
    const float* Pa = yp;
    const float* Pb = yp + KD;
    const float* Pc = yp + 2 * KD;
    const float* A  = yp + 3 * KD;
    const float* B  = A + SZ;
    const int b = blockIdx.x;
    const int t = threadIdx.x;

    if (b == 0) { probs_acc[t] = 0.0f; probs_acc[t + 256] = 0.0f; }

    if (b < 256) {
        // ---- A-pack: j = 2b, 2b+1; each thread handles k0 = 2t, 2t+1 ----
        #pragma unroll
        for (int jj = 0; jj < 2; ++jj) {
            const int j = b * 2 + jj;
            const float pb = Pb[j];
            const int k0 = 2 * t;
            const float4* src = (const float4*)(A + ((size_t)j * KD + k0) * 8);
            float av[16];
            ((float4*)av)[0] = src[0];
            ((float4*)av)[1] = src[1];
            ((float4*)av)[2] = src[2];
            ((float4*)av)[3] = src[3];
            const float s0 = pb * Pc[k0];
            const float s1 = pb * Pc[k0 + 1];
            const size_t fo = (size_t)(k0 >> 5) * 16384 + (size_t)(j >> 4) * 512
                            + (size_t)((k0 >> 3) & 3) * 128 + (j & 15) * 8 + (k0 & 7);
            #pragma unroll
            for (int x = 0; x < 8; ++x) {
                ushort2 w;
                w.x = f2bf(av[x] * s0);
                w.y = f2bf(av[8 + x] * s1);
                *(ushort2*)(Wbf + (size_t)x * PLANE + fo) = w;
            }
        }
    } else {
        // ---- B-pack: transpose [k][i] -> [i][k] through swizzled LDS ----
        const int tb = b - 256;
        const int k0 = (tb / 16) * 32;
        const int i0 = (tb % 16) * 32;
        char* ldsb = (char*)lds;
        #pragma unroll
        for (int p = 0; p < 4; ++p) {
            const int idx = t + p * 256;
            const int dk = idx >> 5;
            const int di = idx & 31;
            const float pa = Pa[i0 + di];
            const float4* src = (const float4*)(B + ((size_t)(k0 + dk) * KD + (i0 + di)) * 8);
            float bv[8];
            ((float4*)bv)[0] = src[0];
            ((float4*)bv)[1] = src[1];
            const int swz = (di & 7) << 4;
            #pragma unroll
            for (int y = 0; y < 8; ++y)
                *(unsigned short*)(ldsb + (y * 32 + di) * 64 + ((dk * 2) ^ swz)) =
                    f2bf(bv[y] * pa);
        }
        __syncthreads();
        #pragma unroll
        for (int p = 0; p < 4; ++p) {
            const int c = t + p * 256;
            const int y = c >> 7;
            const int rem = c & 127;
            const int di = rem >> 2;
            const int dk8 = (rem & 3) * 8;
            uint4 v = *(const uint4*)(ldsb + (y * 32 + di) * 64 + ((dk8 * 2) ^ ((di & 7) << 4)));
            const size_t fo = (size_t)(k0 >> 5) * 16384 + (size_t)((i0 + di) >> 4) * 512
                            + (size_t)(dk8 >> 3) * 128 + (di & 15) * 8;
            *(uint4*)(Xbf + (size_t)y * PLANE + fo) = v;
        }
    }
}

// ---------------------------------------------------------------------------
// Fused GEMM + C-contraction — BIG-TILE / ONE-ROUND decomposition.
// R2..R7: three different schedules, all ~40 us -> the shared bottleneck is
// the 64x64-tile decomposition (compute/fetch 1 KFLOP/B, ~32K VMEM tx/CU,
// uneven 1024-block grid with a straggler round).  New shape:
//   128x128 ij-tile x 2x2 xy per block, 512 threads (8 waves = 2M x 4N),
//   grid = 256 = EXACTLY 1 block/CU, one round, no tail.
// Per K=32 step: stage 32 fragment lines (32 KB, linear copies of the
// k-major layout -> conflict-free ds_read, no swizzle), 32 MFMA/wave.
// Counted-vmcnt double buffer (depth 2, vmcnt(4), never 0 mid-loop) since
// at 1 block/CU there is no inter-block TLP.
// XCD swizzle: xcd = bid&7 owns 2 ij-tiles sharing i_t x all 16 xy-groups;
// per-XCD working set: X 1 MB + W 2 MB + C 1 MB = 4 MB = one L2.
// ---------------------------------------------------------------------------
__global__ __launch_bounds__(512, 2) void gemm_kernel(const float* __restrict__ yp,
                                                      const unsigned short* __restrict__ Wbf,
                                                      const unsigned short* __restrict__ Xbf,
                                                      float* __restrict__ probs_acc) {
    __shared__ unsigned short S[2][32 * 512];   // dbuf x 32 fragment lines (32 KB)
    __shared__ float red[8][32];

    const int bid = blockIdx.x;
    const int xcd = bid & 7;
    const int local = bid >> 3;          // 0..31
    const int tl = local >> 4;           // 0..1
    const int group = local & 15;        // 0..15 xy-group
    const int i_t = xcd >> 1;                    // 0..3
    const int j_t = ((xcd & 1) << 1) | tl;       // 0..3
    const int i0 = i_t * 128, j0 = j_t * 128;
    const int x0 = (group >> 2) * 2, y0 = (group & 3) * 2;

    const int t = threadIdx.x;
    const int w = t >> 6;            // wave 0..7
    const int l = t & 63;
    const int wm = w >> 2, wn = w & 3;   // 2M x 4N wave grid
    const int lm = l & 15, quad = l >> 4;

    // staging: wave w copies fragment lines idx = w*4+q (q=0..3) per k-step.
    // idx>>3 = tile {0,1:X(dy) 2,3:W(dx)}, idx&7 = rt within the 128-row band.
    const unsigned short* gq[4];   // per-q source (lane-offset, kc=0)
    #pragma unroll
    for (int q = 0; q < 4; ++q) {
        const int idx = w * 4 + q;
        const int tile = idx >> 3;
        const int rt = idx & 7;
        if (tile < 2)
            gq[q] = Xbf + (size_t)(y0 + tile) * PLANE + (size_t)(i0 / 16 + rt) * 512 + l * 8;
        else
            gq[q] = Wbf + (size_t)(x0 + (tile - 2)) * PLANE + (size_t)(j0 / 16 + rt) * 512 + l * 8;
    }
    const int sbase = (w * 4) * 512;   // LDS elem offset of this wave's 4 lines

    v4f acc[2][2][4][2];   // [dy][dx][mt][nt]
    #pragma unroll
    for (int a = 0; a < 2; ++a)
      #pragma unroll
      for (int bb = 0; bb < 2; ++bb)
        #pragma unroll
        for (int c = 0; c < 4; ++c)
          #pragma unroll
          for (int d = 0; d < 2; ++d)
            acc[a][bb][c][d] = (v4f){0.f, 0.f, 0.f, 0.f};

    // prologue: stage kc=0 -> buf0, kc=1 -> buf1; wait for buf0 only.
    #pragma unroll
    for (int q = 0; q < 4; ++q) async16(gq[q], &S[0][sbase + q * 512]);
    #pragma unroll
    for (int q = 0; q < 4; ++q) async16(gq[q] + 16384, &S[1][sbase + q * 512]);
    asm volatile("s_waitcnt vmcnt(4)" ::: "memory");
    bar();

    for (int kc = 0; kc < 16; ++kc) {
        const int cur = kc & 1;
        v8s aF[2][4], bF[2][2];
        #pragma unroll
        for (int dy = 0; dy < 2; ++dy)
            #pragma unroll
            for (int mt = 0; mt < 4; ++mt)
                aF[dy][mt] = *(const v8s*)&S[cur][(dy * 8 + wm * 4 + mt) * 512 + l * 8];
        #pragma unroll
        for (int dx = 0; dx < 2; ++dx)
            #pragma unroll
            for (int nt = 0; nt < 2; ++nt)
                bF[dx][nt] = *(const v8s*)&S[cur][((2 + dx) * 8 + wn * 2 + nt) * 512 + l * 8];
        __builtin_amdgcn_s_setprio(1);
        #pragma unroll
        for (int dy = 0; dy < 2; ++dy)
            #pragma unroll
            for (int dx = 0; dx < 2; ++dx)
                #pragma unroll
                for (int mt = 0; mt < 4; ++mt)
                    #pragma unroll
                    for (int nt = 0; nt < 2; ++nt)
                        acc[dy][dx][mt][nt] = __builtin_amdgcn_mfma_f32_16x16x32_bf16(
                            aF[dy][mt], bF[dx][nt], acc[dy][dx][mt][nt], 0, 0, 0);
        __builtin_amdgcn_s_setprio(0);
        bar();   // all waves done reading S[cur]
        if (kc + 2 < 16) {
            const size_t kb = (size_t)(kc + 2) * 16384;
            #pragma unroll
            for (int q = 0; q < 4; ++q) async16(gq[q] + kb, &S[cur][sbase + q * 512]);
        }
        if (kc < 15) {
            if (kc + 2 < 16) asm volatile("s_waitcnt vmcnt(4)" ::: "memory");
            else             asm volatile("s_waitcnt vmcnt(0)" ::: "memory");
            bar();
        }
    }

    // ---- epilogue: contract 4 T tiles with shared C[i,j,0..7] (fp32, L2) ----
    const float* Cp = yp + 3 * KD + 2 * (size_t)SZ;
    float zacc[2][2][8];
    #pragma unroll
    for (int dy = 0; dy < 2; ++dy)
      #pragma unroll
      for (int dx = 0; dx < 2; ++dx)
        #pragma unroll
        for (int z = 0; z < 8; ++z) zacc[dy][dx][z] = 0.f;

    #pragma unroll
    for (int mt = 0; mt < 4; ++mt) {
        #pragma unroll
        for (int nt = 0; nt < 2; ++nt) {
            #pragma unroll
            for (int r = 0; r < 4; ++r) {
                const int gi = i0 + wm * 64 + mt * 16 + quad * 4 + r;  // D row = i
                const int gj = j0 + wn * 32 + nt * 16 + lm;            // D col = j
                const float4* cp = (const float4*)(Cp + ((size_t)gi * KD + gj) * 8);
                const float4 c0 = cp[0], c1 = cp[1];
                #pragma unroll
                for (int dy = 0; dy < 2; ++dy) {
                    #pragma unroll
                    for (int dx = 0; dx < 2; ++dx) {
                        const float tv = acc[dy][dx][mt][nt][r];
                        zacc[dy][dx][0] += tv * c0.x; zacc[dy][dx][1] += tv * c0.y;
                        zacc[dy][dx][2] += tv * c0.z; zacc[dy][dx][3] += tv * c0.w;
                        zacc[dy][dx][4] += tv * c1.x; zacc[dy][dx][5] += tv * c1.y;
                        zacc[dy][dx][6] += tv * c1.z; zacc[dy][dx][7] += tv * c1.w;
                    }
                }
            }
        }
    }
    #pragma unroll
    for (int dy = 0; dy < 2; ++dy)
      #pragma unroll
      for (int dx = 0; dx < 2; ++dx)
        #pragma unroll
        for (int z = 0; z < 8; ++z) {
            float v = zacc[dy][dx][z];
            for (int off = 32; off > 0; off >>= 1)
                v += __shfl_xor(v, off, 64);
            zacc[dy][dx][z] = v;
        }
    if (l == 0) {
        #pragma unroll
        for (int dy = 0; dy < 2; ++dy)
          #pragma unroll
          for (int dx = 0; dx < 2; ++dx)
            #pragma unroll
            for (int z = 0; z < 8; ++z)
                red[w][(dy * 2 + dx) * 8 + z] = zacc[dy][dx][z];
    }
    __syncthreads();
    if (t < 32) {
        float s = 0.f;
        #pragma unroll
        for (int ww = 0; ww < 8; ++ww) s += red[ww][t];
        const int p = t >> 3;              // dy*2+dx
        const int dy = p >> 1, dx = p & 1, z = t & 7;
        atomicAdd(&probs_acc[((x0 + dx) * 8 + (y0 + dy)) * 8 + z], s);
    }
}

// ---------------------------------------------------------------------------
// Finalize: KL divergence + emit probs. out[0]=d, out[1..512]=probs.
// ---------------------------------------------------------------------------
__global__ __launch_bounds__(512) void finalize_kernel(const float* __restrict__ probs_acc,
                                                       const float* __restrict__ y_true,
                                                       float* __restrict__ out) {
    __shared__ float red[8];
    const int t = threadIdx.x;
    const float p = probs_acc[t];
    out[1 + t] = p;
    const float ytv = y_true[t];
    const float pc = fminf(fmaxf(p, 1e-10f), 1.0f);
    float term = ytv * (logf(ytv + 1e-10f) - logf(pc));
    for (int off = 32; off > 0; off >>= 1)
        term += __shfl_xor(term, off, 64);
    if ((t & 63) == 0) red[t >> 6] = term;
    __syncthreads();
    if (t == 0) {
        float s = 0.f;
        #pragma unroll
        for (int i = 0; i < 8; ++i) s += red[i];
        out[0] = s;
    }
}

extern "C" void kernel_launch(void* const* d_in, const int* in_sizes, int n_in,
                              void* d_out, int out_size, void* d_ws, size_t ws_size,
                              hipStream_t stream) {
    const float* yp = (const float*)d_in[0];
    const float* yt = (const float*)d_in[1];
    float* out = (float*)d_out;

    unsigned short* Wbf = (unsigned short*)d_ws;              // 8 planes of A-weighted: 4 MB
    unsigned short* Xbf = Wbf + (size_t)8 * PLANE;            // 8 planes of B-weighted: 4 MB
    float* probs_acc = (float*)(Xbf + (size_t)8 * PLANE);     // 512 floats

    pack_kernel<<<512, 256, 0, stream>>>(yp, Wbf, Xbf, probs_acc);
    gemm_kernel<<<256, 512, 0, stream>>>(yp, Wbf, Xbf, probs_acc);
    finalize_kernel<<<1, 512, 0, stream>>>(probs_acc, yt, out);
}

// Round 9
// 100.246 us; speedup vs baseline: 1.0468x; 1.0210x over previous
//
#include <hip/hip_runtime.h>
#include <hip/hip_bf16.h>
#include <stdint.h>

#define KD 512
#define OD 8
#define SZ (KD*KD*OD)       // 2097152 elements per tensor (A,B,C)
#define PLANE (KD*KD)       // 262144

typedef short v8s __attribute__((ext_vector_type(8)));
typedef float v4f __attribute__((ext_vector_type(4)));

#define GLOBAL_AS __attribute__((address_space(1)))
#define LDS_AS __attribute__((address_space(3)))

static __device__ __forceinline__ unsigned short f2bf(float f) {
    union { float f; unsigned int u; } v; v.f = f;
    unsigned int u = v.u;
    unsigned int r = u + 0x7FFF + ((u >> 16) & 1);   // RNE
    return (unsigned short)(r >> 16);
}

static __device__ __forceinline__ void async16(const unsigned short* g, unsigned short* l) {
    __builtin_amdgcn_global_load_lds((const GLOBAL_AS void*)g, (LDS_AS void*)l, 16, 0, 0);
}

static __device__ __forceinline__ void bar() {
    __builtin_amdgcn_sched_barrier(0);
    __builtin_amdgcn_s_barrier();
    __builtin_amdgcn_sched_barrier(0);
}

// ---------------------------------------------------------------------------
// FRAGMENT LAYOUT v2 (k-major): one MFMA operand fragment (16 rows x 32 k)
// = 512 contiguous elems (1 KB):
//   elem_off = p*PLANE + (k>>5)*16384 + (r>>4)*512
//            + ((k>>3)&3)*128 + (r&15)*8 + (k&7)
// lane l owns elems [l*8, l*8+8), l = (r&15) + ((k>>3)&3)*16 — the
// mfma_f32_16x16x32_bf16 operand map (verified: R6-R8 passed).
// ---------------------------------------------------------------------------

// ---------------------------------------------------------------------------
// Pack (R9): A-pack REWRITTEN for fully-coalesced full-line output.
// R6-R8's A-pack wrote scattered 4-B pieces at 16-B granularity with
// adjacent pieces of one 64-B line owned by different blocks (=> different
// XCDs): partial-line cross-die RMW — the prime suspect for a hidden
// 20-30 us pack.  Now: block = (jt: 16 j-rows) x (kb: 64 k).
//   phase 1: coalesced A reads -> LDS [j16][x8][k64], k ^= (j&7)<<3 swizzle
//   phase 2: each wave emits one complete 1 KB fragment line per store
//            (64 lanes x dwordx4, contiguous) — full lines, no sharing.
// B-pack unchanged (its uint4 stores already cover full 64-B lines).
// blocks [0,256): A-pack. [256,512): B-pack. block 0 zeroes probs_acc.
// ---------------------------------------------------------------------------
__global__ __launch_bounds__(256) void pack_kernel(const float* __restrict__ yp,
                                                   unsigned short* __restrict__ Wbf,
                                                   unsigned short* __restrict__ Xbf,
                                                   float* __restrict__ probs_acc) {
    __shared__ unsigned short lds[8192];   // A: [j16][x8][k64] swz; B: [y8][di32][dk32]
    const float* Pa = yp;
    const float* Pb = yp + KD;
    const float* Pc = yp + 2 * KD;
    const float* A  = yp + 3 * KD;
    const float* B  = A + SZ;
    const int b = blockIdx.x;
    const int t = threadIdx.x;

    if (b == 0) { probs_acc[t] = 0.0f; probs_acc[t + 256] = 0.0f; }

    if (b < 256) {
        // ---- A-pack: jt = b>>3 (16 j), kb = b&7 (64 k) ----
        const int jt = b >> 3, kb = b & 7;
        const int j0 = jt * 16, k0 = kb * 64;
        // phase 1: 512 (j, k-pair) cells; cell = cc*256 + t
        #pragma unroll
        for (int cc = 0; cc < 2; ++cc) {
            const int cell = cc * 256 + t;
            const int kl = (cell & 31) * 2;      // k_local pair base (0..62)
            const int jl = cell >> 5;            // 0..15
            const int j = j0 + jl, k = k0 + kl;
            const float pb = Pb[j];
            const float s0 = pb * Pc[k];
            const float s1 = pb * Pc[k + 1];
            const float4* src = (const float4*)(A + ((size_t)j * KD + k) * 8);
            float av[16];
            ((float4*)av)[0] = src[0];
            ((float4*)av)[1] = src[1];
            ((float4*)av)[2] = src[2];
            ((float4*)av)[3] = src[3];
            const int swz = (jl & 7) << 3;
            #pragma unroll
            for (int x = 0; x < 8; ++x) {
                ushort2 wv;
                wv.x = f2bf(av[x] * s0);         // k
                wv.y = f2bf(av[8 + x] * s1);     // k+1
                *(ushort2*)&lds[jl * 512 + x * 64 + (kl ^ swz)] = wv;
            }
        }
        __syncthreads();
        // phase 2: 1024 16-B slots; each wave = one (x,kcc) 1 KB line.
        #pragma unroll
        for (int ss = 0; ss < 4; ++ss) {
            const int slot = ss * 256 + t;
            const int x = slot >> 7;
            const int kcc = (slot >> 6) & 1;
            const int l = slot & 63;
            const int jl = l & 15, kq = l >> 4;
            const int klocal = kcc * 32 + kq * 8;
            const int swz = (jl & 7) << 3;
            uint4 v = *(const uint4*)&lds[jl * 512 + x * 64 + (klocal ^ swz)];
            const size_t fo = (size_t)(kb * 2 + kcc) * 16384 + (size_t)jt * 512 + l * 8;
            *(uint4*)(Wbf + (size_t)x * PLANE + fo) = v;
        }
    } else {
        // ---- B-pack: transpose [k][i] -> fragment layout via swizzled LDS ----
        const int tb = b - 256;
        const int k0 = (tb / 16) * 32;
        const int i0 = (tb % 16) * 32;
        char* ldsb = (char*)lds;
        #pragma unroll
        for (int p = 0; p < 4; ++p) {
            const int idx = t + p * 256;
            const int dk = idx >> 5;
            const int di = idx & 31;
            const float pa = Pa[i0 + di];
            const float4* src = (const float4*)(B + ((size_t)(k0 + dk) * KD + (i0 + di)) * 8);
            float bv[8];
            ((float4*)bv)[0] = src[0];
            ((float4*)bv)[1] = src[1];
            const int swz = (di & 7) << 4;
            #pragma unroll
            for (int y = 0; y < 8; ++y)
                *(unsigned short*)(ldsb + (y * 32 + di) * 64 + ((dk * 2) ^ swz)) =
                    f2bf(bv[y] * pa);
        }
        __syncthreads();
        #pragma unroll
        for (int p = 0; p < 4; ++p) {
            const int c = t + p * 256;
            const int y = c >> 7;
            const int rem = c & 127;
            const int di = rem >> 2;
            const int dk8 = (rem & 3) * 8;
            uint4 v = *(const uint4*)(ldsb + (y * 32 + di) * 64 + ((dk8 * 2) ^ ((di & 7) << 4)));
            const size_t fo = (size_t)(k0 >> 5) * 16384 + (size_t)((i0 + di) >> 4) * 512
                            + (size_t)(dk8 >> 3) * 128 + (di & 15) * 8;
            *(uint4*)(Xbf + (size_t)y * PLANE + fo) = v;
        }
    }
}

// ---------------------------------------------------------------------------
// Fused GEMM + C-contraction — BIG-TILE / ONE-ROUND (identical to R8).
// 128x128 ij-tile x 2x2 xy per block, 512 threads (8 waves, 2M x 4N),
// grid = 256 = 1 block/CU.  Counted-vmcnt double buffer.  XCD swizzle.
// ---------------------------------------------------------------------------
__global__ __launch_bounds__(512, 2) void gemm_kernel(const float* __restrict__ yp,
                                                      const unsigned short* __restrict__ Wbf,
                                                      const unsigned short* __restrict__ Xbf,
                                                      float* __restrict__ probs_acc) {
    __shared__ unsigned short S[2][32 * 512];   // dbuf x 32 fragment lines (32 KB)
    __shared__ float red[8][32];

    const int bid = blockIdx.x;
    const int xcd = bid & 7;
    const int local = bid >> 3;          // 0..31
    const int tl = local >> 4;           // 0..1
    const int group = local & 15;        // 0..15 xy-group
    const int i_t = xcd >> 1;                    // 0..3
    const int j_t = ((xcd & 1) << 1) | tl;       // 0..3
    const int i0 = i_t * 128, j0 = j_t * 128;
    const int x0 = (group >> 2) * 2, y0 = (group & 3) * 2;

    const int t = threadIdx.x;
    const int w = t >> 6;            // wave 0..7
    const int l = t & 63;
    const int wm = w >> 2, wn = w & 3;   // 2M x 4N wave grid
    const int lm = l & 15, quad = l >> 4;

    const unsigned short* gq[4];   // per-q staging source (lane-offset, kc=0)
    #pragma unroll
    for (int q = 0; q < 4; ++q) {
        const int idx = w * 4 + q;
        const int tile = idx >> 3;
        const int rt = idx & 7;
        if (tile < 2)
            gq[q] = Xbf + (size_t)(y0 + tile) * PLANE + (size_t)(i0 / 16 + rt) * 512 + l * 8;
        else
            gq[q] = Wbf + (size_t)(x0 + (tile - 2)) * PLANE + (size_t)(j0 / 16 + rt) * 512 + l * 8;
    }
    const int sbase = (w * 4) * 512;

    v4f acc[2][2][4][2];   // [dy][dx][mt][nt]
    #pragma unroll
    for (int a = 0; a < 2; ++a)
      #pragma unroll
      for (int bb = 0; bb < 2; ++bb)
        #pragma unroll
        for (int c = 0; c < 4; ++c)
          #pragma unroll
          for (int d = 0; d < 2; ++d)
            acc[a][bb][c][d] = (v4f){0.f, 0.f, 0.f, 0.f};

    #pragma unroll
    for (int q = 0; q < 4; ++q) async16(gq[q], &S[0][sbase + q * 512]);
    #pragma unroll
    for (int q = 0; q < 4; ++q) async16(gq[q] + 16384, &S[1][sbase + q * 512]);
    asm volatile("s_waitcnt vmcnt(4)" ::: "memory");
    bar();

    for (int kc = 0; kc < 16; ++kc) {
        const int cur = kc & 1;
        v8s aF[2][4], bF[2][2];
        #pragma unroll
        for (int dy = 0; dy < 2; ++dy)
            #pragma unroll
            for (int mt = 0; mt < 4; ++mt)
                aF[dy][mt] = *(const v8s*)&S[cur][(dy * 8 + wm * 4 + mt) * 512 + l * 8];
        #pragma unroll
        for (int dx = 0; dx < 2; ++dx)
            #pragma unroll
            for (int nt = 0; nt < 2; ++nt)
                bF[dx][nt] = *(const v8s*)&S[cur][((2 + dx) * 8 + wn * 2 + nt) * 512 + l * 8];
        __builtin_amdgcn_s_setprio(1);
        #pragma unroll
        for (int dy = 0; dy < 2; ++dy)
            #pragma unroll
            for (int dx = 0; dx < 2; ++dx)
                #pragma unroll
                for (int mt = 0; mt < 4; ++mt)
                    #pragma unroll
                    for (int nt = 0; nt < 2; ++nt)
                        acc[dy][dx][mt][nt] = __builtin_amdgcn_mfma_f32_16x16x32_bf16(
                            aF[dy][mt], bF[dx][nt], acc[dy][dx][mt][nt], 0, 0, 0);
        __builtin_amdgcn_s_setprio(0);
        bar();   // all waves done reading S[cur]
        if (kc + 2 < 16) {
            const size_t kb = (size_t)(kc + 2) * 16384;
            #pragma unroll
            for (int q = 0; q < 4; ++q) async16(gq[q] + kb, &S[cur][sbase + q * 512]);
        }
        if (kc < 15) {
            if (kc + 2 < 16) asm volatile("s_waitcnt vmcnt(4)" ::: "memory");
            else             asm volatile("s_waitcnt vmcnt(0)" ::: "memory");
            bar();
        }
    }

    // ---- epilogue: contract 4 T tiles with shared C[i,j,0..7] (fp32, L2) ----
    const float* Cp = yp + 3 * KD + 2 * (size_t)SZ;
    float zacc[2][2][8];
    #pragma unroll
    for (int dy = 0; dy < 2; ++dy)
      #pragma unroll
      for (int dx = 0; dx < 2; ++dx)
        #pragma unroll
        for (int z = 0; z < 8; ++z) zacc[dy][dx][z] = 0.f;

    #pragma unroll
    for (int mt = 0; mt < 4; ++mt) {
        #pragma unroll
        for (int nt = 0; nt < 2; ++nt) {
            #pragma unroll
            for (int r = 0; r < 4; ++r) {
                const int gi = i0 + wm * 64 + mt * 16 + quad * 4 + r;  // D row = i
                const int gj = j0 + wn * 32 + nt * 16 + lm;            // D col = j
                const float4* cp = (const float4*)(Cp + ((size_t)gi * KD + gj) * 8);
                const float4 c0 = cp[0], c1 = cp[1];
                #pragma unroll
                for (int dy = 0; dy < 2; ++dy) {
                    #pragma unroll
                    for (int dx = 0; dx < 2; ++dx) {
                        const float tv = acc[dy][dx][mt][nt][r];
                        zacc[dy][dx][0] += tv * c0.x; zacc[dy][dx][1] += tv * c0.y;
                        zacc[dy][dx][2] += tv * c0.z; zacc[dy][dx][3] += tv * c0.w;
                        zacc[dy][dx][4] += tv * c1.x; zacc[dy][dx][5] += tv * c1.y;
                        zacc[dy][dx][6] += tv * c1.z; zacc[dy][dx][7] += tv * c1.w;
                    }
                }
            }
        }
    }
    #pragma unroll
    for (int dy = 0; dy < 2; ++dy)
      #pragma unroll
      for (int dx = 0; dx < 2; ++dx)
        #pragma unroll
        for (int z = 0; z < 8; ++z) {
            float v = zacc[dy][dx][z];
            for (int off = 32; off > 0; off >>= 1)
                v += __shfl_xor(v, off, 64);
            zacc[dy][dx][z] = v;
        }
    if (l == 0) {
        #pragma unroll
        for (int dy = 0; dy < 2; ++dy)
          #pragma unroll
          for (int dx = 0; dx < 2; ++dx)
            #pragma unroll
            for (int z = 0; z < 8; ++z)
                red[w][(dy * 2 + dx) * 8 + z] = zacc[dy][dx][z];
    }
    __syncthreads();
    if (t < 32) {
        float s = 0.f;
        #pragma unroll
        for (int ww = 0; ww < 8; ++ww) s += red[ww][t];
        const int p = t >> 3;              // dy*2+dx
        const int dy = p >> 1, dx = p & 1, z = t & 7;
        atomicAdd(&probs_acc[((x0 + dx) * 8 + (y0 + dy)) * 8 + z], s);
    }
}

// ---------------------------------------------------------------------------
// Finalize: KL divergence + emit probs. out[0]=d, out[1..512]=probs.
// ---------------------------------------------------------------------------
__global__ __launch_bounds__(512) void finalize_kernel(const float* __restrict__ probs_acc,
                                                       const float* __restrict__ y_true,
                                                       float* __restrict__ out) {
    __shared__ float red[8];
    const int t = threadIdx.x;
    const float p = probs_acc[t];
    out[1 + t] = p;
    const float ytv = y_true[t];
    const float pc = fminf(fmaxf(p, 1e-10f), 1.0f);
    float term = ytv * (logf(ytv + 1e-10f) - logf(pc));
    for (int off = 32; off > 0; off >>= 1)
        term += __shfl_xor(term, off, 64);
    if ((t & 63) == 0) red[t >> 6] = term;
    __syncthreads();
    if (t == 0) {
        float s = 0.f;
        #pragma unroll
        for (int i = 0; i < 8; ++i) s += red[i];
        out[0] = s;
    }
}

extern "C" void kernel_launch(void* const* d_in, const int* in_sizes, int n_in,
                              void* d_out, int out_size, void* d_ws, size_t ws_size,
                              hipStream_t stream) {
    const float* yp = (const float*)d_in[0];
    const float* yt = (const float*)d_in[1];
    float* out = (float*)d_out;

    unsigned short* Wbf = (unsigned short*)d_ws;              // 8 planes of A-weighted: 4 MB
    unsigned short* Xbf = Wbf + (size_t)8 * PLANE;            // 8 planes of B-weighted: 4 MB
    float* probs_acc = (float*)(Xbf + (size_t)8 * PLANE);     // 512 floats

    pack_kernel<<<512, 256, 0, stream>>>(yp, Wbf, Xbf, probs_acc);
    gemm_kernel<<<256, 512, 0, stream>>>(yp, Wbf, Xbf, probs_acc);
    finalize_kernel<<<1, 512, 0, stream>>>(probs_acc, yt, out);
}